// Round 12
// baseline (1602.392 us; speedup 1.0000x reference)
//
#include <hip/hip_runtime.h>

typedef _Float16 f16;
typedef _Float16 half4 __attribute__((ext_vector_type(4)));
typedef _Float16 half8 __attribute__((ext_vector_type(8)));
typedef float f32x4 __attribute__((ext_vector_type(4)));

typedef __attribute__((address_space(1))) void* as1v;
typedef __attribute__((address_space(3))) void* as3v;

#define SCALE 0.08838834764831845f  // 1/sqrt(128)

static __device__ __forceinline__ f32x4 mfma16(half8 a, half8 b, f32x4 c){
  return __builtin_amdgcn_mfma_f32_16x16x32_f16(a, b, c, 0, 0, 0);
}

// ---------------- weight fp32 -> fp16 ----------------
__global__ __launch_bounds__(256) void k_cvt(const float* __restrict__ src, f16* __restrict__ dst, int n){
  int i = (blockIdx.x * 256 + threadIdx.x) * 8;
  if (i >= n) return;
  float4 a = *(const float4*)(src + i);
  float4 b = *(const float4*)(src + i + 4);
  half8 h;
  h[0] = (f16)a.x; h[1] = (f16)a.y; h[2] = (f16)a.z; h[3] = (f16)a.w;
  h[4] = (f16)b.x; h[5] = (f16)b.y; h[6] = (f16)b.z; h[7] = (f16)b.w;
  *(half8*)(dst + i) = h;
}

// ---------------- LN over protos, (M,C,D) -> chunk-local (cl,m,D) fp16 ----------------
__global__ __launch_bounds__(256) void k_ln0(const float* __restrict__ protos,
                                             const float* __restrict__ g,
                                             const float* __restrict__ bb,
                                             f16* __restrict__ xb, int c0){
  const int w = threadIdx.x >> 6, l = threadIdx.x & 63;
  const int q = blockIdx.x * 4 + w;
  const int cl = q >> 6, m = q & 63;
  const float* in = protos + ((size_t)m * 2000 + (size_t)(c0 + cl)) * 512;
  const int d0 = l * 8;
  float4 a = *(const float4*)(in + d0);
  float4 c = *(const float4*)(in + d0 + 4);
  float s  = a.x + a.y + a.z + a.w + c.x + c.y + c.z + c.w;
  float ss = a.x*a.x + a.y*a.y + a.z*a.z + a.w*a.w + c.x*c.x + c.y*c.y + c.z*c.z + c.w*c.w;
#pragma unroll
  for (int msk = 1; msk < 64; msk <<= 1){ s += __shfl_xor(s, msk); ss += __shfl_xor(ss, msk); }
  const float mu = s * (1.f/512.f);
  const float rs = rsqrtf(ss * (1.f/512.f) - mu*mu + 1e-5f);
  float4 g0 = *(const float4*)(g + d0),  g1 = *(const float4*)(g + d0 + 4);
  float4 b0 = *(const float4*)(bb + d0), b1 = *(const float4*)(bb + d0 + 4);
  half8 o;
  o[0] = (f16)((a.x - mu) * rs * g0.x + b0.x);
  o[1] = (f16)((a.y - mu) * rs * g0.y + b0.y);
  o[2] = (f16)((a.z - mu) * rs * g0.z + b0.z);
  o[3] = (f16)((a.w - mu) * rs * g0.w + b0.w);
  o[4] = (f16)((c.x - mu) * rs * g1.x + b1.x);
  o[5] = (f16)((c.y - mu) * rs * g1.y + b1.y);
  o[6] = (f16)((c.z - mu) * rs * g1.z + b1.z);
  o[7] = (f16)((c.w - mu) * rs * g1.w + b1.w);
  *(half8*)(xb + (size_t)q * 512 + d0) = o;
}

// ---------------- residual + LN:  out = LN(t_f16 + skip_f16) ----------------
__global__ __launch_bounds__(256) void k_resln(const f16* __restrict__ t, const f16* __restrict__ skip,
                                               const float* __restrict__ g, const float* __restrict__ bb,
                                               f16* __restrict__ outp){
  const int w = threadIdx.x >> 6, l = threadIdx.x & 63;
  const size_t q = (size_t)blockIdx.x * 4 + w;
  const int d0 = l * 8;
  half8 tv = *(const half8*)(t + q * 512 + d0);
  half8 sk = *(const half8*)(skip + q * 512 + d0);
  float v0 = (float)tv[0] + (float)sk[0], v1 = (float)tv[1] + (float)sk[1];
  float v2 = (float)tv[2] + (float)sk[2], v3 = (float)tv[3] + (float)sk[3];
  float v4 = (float)tv[4] + (float)sk[4], v5 = (float)tv[5] + (float)sk[5];
  float v6 = (float)tv[6] + (float)sk[6], v7 = (float)tv[7] + (float)sk[7];
  float s  = v0+v1+v2+v3+v4+v5+v6+v7;
  float ss = v0*v0+v1*v1+v2*v2+v3*v3+v4*v4+v5*v5+v6*v6+v7*v7;
#pragma unroll
  for (int msk = 1; msk < 64; msk <<= 1){ s += __shfl_xor(s, msk); ss += __shfl_xor(ss, msk); }
  const float mu = s * (1.f/512.f);
  const float rs = rsqrtf(ss * (1.f/512.f) - mu*mu + 1e-5f);
  float4 g0 = *(const float4*)(g + d0),  g1 = *(const float4*)(g + d0 + 4);
  float4 b0 = *(const float4*)(bb + d0), b1 = *(const float4*)(bb + d0 + 4);
  half8 o;
  o[0] = (f16)((v0 - mu) * rs * g0.x + b0.x);
  o[1] = (f16)((v1 - mu) * rs * g0.y + b0.y);
  o[2] = (f16)((v2 - mu) * rs * g0.z + b0.z);
  o[3] = (f16)((v3 - mu) * rs * g0.w + b0.w);
  o[4] = (f16)((v4 - mu) * rs * g1.x + b1.x);
  o[5] = (f16)((v5 - mu) * rs * g1.y + b1.y);
  o[6] = (f16)((v6 - mu) * rs * g1.z + b1.z);
  o[7] = (f16)((v7 - mu) * rs * g1.w + b1.w);
  *(half8*)(outp + q * 512 + d0) = o;
}

// ---------------- persistent-strip GEMM (r8 inner loop): C = A B^T + bias ----
// Grid = 512 blocks (2/CU). Each block sweeps a CONTIGUOUS chunk of (tm,tn)
// tiles (tm-major -> B-panel stays L1/L2-hot across the strip) with the K-loop
// FLATTENED across tiles: the 4-phase schedule, 2-dbuf ring, staging stream
// and counted vmcnt(2) run uninterrupted across tile boundaries; the C-write
// epilogue fires in-loop and overlaps the next tile's staged loads.
#define GLL(gp, lp) __builtin_amdgcn_global_load_lds((as1v)(void*)(gp), (as3v)(lp), 16, 0, 0)

template<bool RELU>
__global__ __launch_bounds__(512, 2) void k_gemm(const f16* __restrict__ A, const f16* __restrict__ B,
                                                 const float* __restrict__ bias, f16* __restrict__ Cout,
                                                 int N, int K, int gm, int gn){
  extern __shared__ char smem_raw[];
  f16* lds = (f16*)smem_raw;   // 2 bufs x 32768 f16; per buf: A halves @0,8192; B halves @16384,24576

  const int t = threadIdx.x, w = t >> 6, l = t & 63;
  const int wr = w >> 2, wc = w & 3;

  const int ntiles = gm * gn;
  const int nb = gridDim.x;
  const int chunk = ntiles / nb, rem = ntiles - chunk * nb;
  const int b = blockIdx.x;
  const int i0 = b * chunk + (b < rem ? b : rem);
  const int cnt = chunk + (b < rem ? 1 : 0);
  if (cnt == 0) return;

  const int NT = K >> 6;
  const int lnt = __ffs(NT) - 1;
  const int G = cnt * NT;

  f32x4 acc[8][4];
#pragma unroll
  for (int m = 0; m < 8; ++m)
#pragma unroll
    for (int n = 0; n < 4; ++n) acc[m][n] = (f32x4){0.f,0.f,0.f,0.f};

  // staging thread constants (pre-swizzled source slot, rule 21)
  const int lsw = ((t & 7) ^ ((t >> 3) & 7)) * 8;
  const f16* gAt = A + (size_t)(t >> 3) * (size_t)K + lsw;
  const f16* gBt = B + (size_t)(t >> 3) * (size_t)K + lsw;
  const int t8 = t * 8;

  // ds_read lane constants
  const int rA  = (l & 15) * 64;
  const int ps0 = (((l >> 4) ^ (l & 7)) << 3);
  const int ps1 = (((4 + (l >> 4)) ^ (l & 7)) << 3);
  const int abase = wr * 8192 + rA;
  const int bbase = 16384 + wc * 4096 + rA;

  auto stgA = [&](int g, int h){
    if (g >= G) return;
    const int idx = i0 + (g >> lnt);
    const int kt  = g & (NT - 1);
    const int tm  = idx % gm;
    f16* d = lds + (g & 1) * 32768 + h * 8192 + t8;
    const f16* s = gAt + ((size_t)(tm * 256 + h * 128)) * (size_t)K + (size_t)kt * 64;
    GLL(s, d);
    GLL(s + (size_t)64 * K, d + 4096);
  };
  auto stgB = [&](int g, int h){
    if (g >= G) return;
    const int idx = i0 + (g >> lnt);
    const int kt  = g & (NT - 1);
    const int tn  = idx / gm;
    f16* d = lds + (g & 1) * 32768 + 16384 + h * 8192 + t8;
    const f16* s = gBt + ((size_t)(tn * 256 + h * 128)) * (size_t)K + (size_t)kt * 64;
    GLL(s, d);
    GLL(s + (size_t)64 * K, d + 4096);
  };

  // prologue: tile-step 0 fully + A0 of step 1
  stgA(0, 0); stgA(0, 1); stgB(0, 0); stgB(0, 1);
  if (G > 1){
    stgA(1, 0);
    asm volatile("s_waitcnt vmcnt(2)" ::: "memory");
  } else {
    asm volatile("s_waitcnt vmcnt(0)" ::: "memory");
  }
  __builtin_amdgcn_s_barrier();

  for (int g = 0; g < G; ++g){
    const f16* sb = lds + (g & 1) * 32768;
    const bool s1 = g + 1 < G, s2 = g + 2 < G;
    half8 af03[4][2], af47[4][2], bf[4][2];

    // ---- phase 1 ----
#pragma unroll
    for (int m = 0; m < 4; ++m){
      af03[m][0] = *(const half8*)(sb + abase + m * 1024 + ps0);
      af03[m][1] = *(const half8*)(sb + abase + m * 1024 + ps1);
    }
#pragma unroll
    for (int n = 0; n < 2; ++n){
      bf[n][0] = *(const half8*)(sb + bbase + n * 1024 + ps0);
      bf[n][1] = *(const half8*)(sb + bbase + n * 1024 + ps1);
    }
    stgA(g + 1, 1);
    __builtin_amdgcn_s_barrier();
    asm volatile("s_waitcnt lgkmcnt(0)" ::: "memory");
    __builtin_amdgcn_sched_barrier(0);
    __builtin_amdgcn_s_setprio(1);
#pragma unroll
    for (int ks = 0; ks < 2; ++ks)
#pragma unroll
      for (int m = 0; m < 4; ++m)
#pragma unroll
        for (int n = 0; n < 2; ++n)
          acc[m][n] = mfma16(bf[n][ks], af03[m][ks], acc[m][n]);
    __builtin_amdgcn_s_setprio(0);
    __builtin_amdgcn_s_barrier();

    // ---- phase 2 ----
#pragma unroll
    for (int n = 2; n < 4; ++n){
      bf[n][0] = *(const half8*)(sb + bbase + n * 1024 + ps0);
      bf[n][1] = *(const half8*)(sb + bbase + n * 1024 + ps1);
    }
    stgB(g + 1, 0);
    __builtin_amdgcn_s_barrier();
    asm volatile("s_waitcnt lgkmcnt(0)" ::: "memory");
    __builtin_amdgcn_sched_barrier(0);
    __builtin_amdgcn_s_setprio(1);
#pragma unroll
    for (int ks = 0; ks < 2; ++ks)
#pragma unroll
      for (int m = 0; m < 4; ++m)
#pragma unroll
        for (int n = 2; n < 4; ++n)
          acc[m][n] = mfma16(bf[n][ks], af03[m][ks], acc[m][n]);
    __builtin_amdgcn_s_setprio(0);
    __builtin_amdgcn_s_barrier();

    // ---- phase 3 ----
#pragma unroll
    for (int m = 0; m < 4; ++m){
      af47[m][0] = *(const half8*)(sb + abase + (m + 4) * 1024 + ps0);
      af47[m][1] = *(const half8*)(sb + abase + (m + 4) * 1024 + ps1);
    }
    stgB(g + 1, 1);
    __builtin_amdgcn_s_barrier();
    asm volatile("s_waitcnt lgkmcnt(0)" ::: "memory");
    __builtin_amdgcn_sched_barrier(0);
    __builtin_amdgcn_s_setprio(1);
#pragma unroll
    for (int ks = 0; ks < 2; ++ks)
#pragma unroll
      for (int m = 0; m < 4; ++m)
#pragma unroll
        for (int n = 0; n < 2; ++n)
          acc[m + 4][n] = mfma16(bf[n][ks], af47[m][ks], acc[m + 4][n]);
    __builtin_amdgcn_s_setprio(0);
    __builtin_amdgcn_s_barrier();

    // ---- phase 4 ----
    stgA(g + 2, 0);
    __builtin_amdgcn_s_barrier();
    __builtin_amdgcn_s_setprio(1);
#pragma unroll
    for (int ks = 0; ks < 2; ++ks)
#pragma unroll
      for (int m = 0; m < 4; ++m)
#pragma unroll
        for (int n = 2; n < 4; ++n)
          acc[m + 4][n] = mfma16(bf[n][ks], af47[m][ks], acc[m + 4][n]);
    __builtin_amdgcn_s_setprio(0);
    if (s1){
      if (s2) { asm volatile("s_waitcnt vmcnt(2)" ::: "memory"); }
      else    { asm volatile("s_waitcnt vmcnt(0)" ::: "memory"); }
    }
    __builtin_amdgcn_s_barrier();

    // ---- in-loop epilogue at tile end: stores overlap next tile's pipeline ----
    if ((g & (NT - 1)) == NT - 1){
      const int idx = i0 + (g >> lnt);
      const int tm = idx % gm, tn = idx / gm;
      const size_t row0 = (size_t)tm * 256;
      const int col0 = tn * 256;
#pragma unroll
      for (int n = 0; n < 4; ++n){
        const int c = col0 + wc * 64 + n * 16 + ((l >> 4) << 2);
        float4 b4 = *(const float4*)(bias + c);
#pragma unroll
        for (int m = 0; m < 8; ++m){
          const size_t r = row0 + (size_t)(wr * 128 + m * 16 + (l & 15));
          float v0 = acc[m][n][0] + b4.x;
          float v1 = acc[m][n][1] + b4.y;
          float v2 = acc[m][n][2] + b4.z;
          float v3 = acc[m][n][3] + b4.w;
          if (RELU){ v0 = fmaxf(v0, 0.f); v1 = fmaxf(v1, 0.f); v2 = fmaxf(v2, 0.f); v3 = fmaxf(v3, 0.f); }
          half4 h; h[0] = (f16)v0; h[1] = (f16)v1; h[2] = (f16)v2; h[3] = (f16)v3;
          *(half4*)&Cout[r * (size_t)N + c] = h;
          acc[m][n] = (f32x4){0.f,0.f,0.f,0.f};
        }
      }
    }
  }
}

// ---------------- per-class 4-head self-attention (M=64, HD=128) ----------------
__global__ __launch_bounds__(256) void k_attn(const f16* __restrict__ qkv, f16* __restrict__ sa){
  __shared__ __align__(16) f16 P[4][4096];
  __shared__ __align__(16) f16 VT[4][4096];
  const int cl = blockIdx.x;
  const int h = threadIdx.x >> 6, l = threadIdx.x & 63;
  const f16* base = qkv + (size_t)cl * 64 * 1536;
  const f16* Qp = base + h * 128;
  const f16* Kp = base + 512 + h * 128;
  const f16* Vp = base + 1024 + h * 128;

  f32x4 s[4][4];
#pragma unroll
  for (int x = 0; x < 4; ++x)
#pragma unroll
    for (int y = 0; y < 4; ++y) s[x][y] = (f32x4){0.f,0.f,0.f,0.f};
#pragma unroll
  for (int ks = 0; ks < 4; ++ks){
    half8 aq[4], bk[4];
#pragma unroll
    for (int x = 0; x < 4; ++x)
      aq[x] = *(const half8*)&Qp[(size_t)(x * 16 + (l & 15)) * 1536 + ks * 32 + (l >> 4) * 8];
#pragma unroll
    for (int y = 0; y < 4; ++y)
      bk[y] = *(const half8*)&Kp[(size_t)(y * 16 + (l & 15)) * 1536 + ks * 32 + (l >> 4) * 8];
#pragma unroll
    for (int x = 0; x < 4; ++x)
#pragma unroll
      for (int y = 0; y < 4; ++y)
        s[x][y] = mfma16(aq[x], bk[y], s[x][y]);
  }

  char* Pb = (char*)&P[h][0];
#pragma unroll
  for (int x = 0; x < 4; ++x){
#pragma unroll
    for (int j = 0; j < 4; ++j){
      float e0 = s[x][0][j] * SCALE;
      float e1 = s[x][1][j] * SCALE;
      float e2 = s[x][2][j] * SCALE;
      float e3 = s[x][3][j] * SCALE;
      float mx = fmaxf(fmaxf(e0, e1), fmaxf(e2, e3));
#pragma unroll
      for (int msk = 1; msk < 16; msk <<= 1) mx = fmaxf(mx, __shfl_xor(mx, msk));
      e0 = __expf(e0 - mx); e1 = __expf(e1 - mx); e2 = __expf(e2 - mx); e3 = __expf(e3 - mx);
      float sm = e0 + e1 + e2 + e3;
#pragma unroll
      for (int msk = 1; msk < 16; msk <<= 1) sm += __shfl_xor(sm, msk);
      const float inv = 1.f / sm;
      const int row = x * 16 + (l >> 4) * 4 + j;
      const int rb = row * 128 + (l & 15) * 2;
      const int rsw = (row & 7) << 4;
      *(f16*)(Pb + ((rb     ) ^ rsw)) = (f16)(e0 * inv);
      *(f16*)(Pb + ((rb + 32) ^ rsw)) = (f16)(e1 * inv);
      *(f16*)(Pb + ((rb + 64) ^ rsw)) = (f16)(e2 * inv);
      *(f16*)(Pb + ((rb + 96) ^ rsw)) = (f16)(e3 * inv);
    }
  }

  char* Vb = (char*)&VT[h][0];
#pragma unroll
  for (int dh = 0; dh < 2; ++dh){
#pragma unroll
    for (int it = 0; it < 8; ++it){
      const int chunk = it * 64 + l;
      const int m = chunk >> 3, dc = chunk & 7;
      half8 v = *(const half8*)&Vp[(size_t)m * 1536 + dh * 64 + dc * 8];
#pragma unroll
      for (int jj = 0; jj < 8; ++jj){
        const int dd = dc * 8 + jj;
        *(f16*)(Vb + ((dd * 128 + m * 2) ^ ((dd & 7) << 4))) = v[jj];
      }
    }
    __syncthreads();
#pragma unroll
    for (int x = 0; x < 4; ++x){
      const int ar = x * 16 + (l & 15);
      const int ab = ar * 128, sw = (ar & 7) << 4;
      half8 ap0 = *(const half8*)(Pb + ((ab + (l >> 4) * 16) ^ sw));
      half8 ap1 = *(const half8*)(Pb + ((ab + 64 + (l >> 4) * 16) ^ sw));
#pragma unroll
      for (int dt = 0; dt < 4; ++dt){
        const int vr = dt * 16 + (l & 15);
        const int vb = vr * 128, vsw = (vr & 7) << 4;
        half8 b0 = *(const half8*)(Vb + ((vb + (l >> 4) * 16) ^ vsw));
        half8 b1 = *(const half8*)(Vb + ((vb + 64 + (l >> 4) * 16) ^ vsw));
        f32x4 o = (f32x4){0.f,0.f,0.f,0.f};
        o = mfma16(ap0, b0, o);
        o = mfma16(ap1, b1, o);
#pragma unroll
        for (int j = 0; j < 4; ++j){
          const int mrow = x * 16 + (l >> 4) * 4 + j;
          const int dcol = dh * 64 + dt * 16 + (l & 15);
          sa[((size_t)cl * 64 + mrow) * 512 + h * 128 + dcol] = (f16)o[j];
        }
      }
    }
    __syncthreads();
  }
}

// ---------------- fused residual + LN2 + cross-attention -> fp32 out ----------------
// Block = 1 class (4 waves). (a) each wave LNs 16 rows of z = t+skip, storing
// z into XOR-swizzled LDS; (b) per-head cross-attn reads z from LDS.
#define ZOFF(m, cb) (((m) * 1024 + (cb)) ^ (((m) & 7) << 4))
__global__ __launch_bounds__(256) void k_resln_cross(const f16* __restrict__ t, const f16* __restrict__ skip,
                                                     const float* __restrict__ g, const float* __restrict__ bb,
                                                     const float* __restrict__ gq, const int* __restrict__ labels,
                                                     float* __restrict__ out, int c0){
  __shared__ __align__(16) char Z[65536];   // z[64][512] f16, row-swizzled
  const int cl = blockIdx.x;
  const int w = threadIdx.x >> 6, l = threadIdx.x & 63;
  const int cg = c0 + cl;
  const size_t rbase = (size_t)cl * 64 * 512;
  const int d0 = l * 8;

  float4 g0 = *(const float4*)(g + d0),  g1 = *(const float4*)(g + d0 + 4);
  float4 b0 = *(const float4*)(bb + d0), b1 = *(const float4*)(bb + d0 + 4);

#pragma unroll 4
  for (int i = 0; i < 16; ++i){
    const int m = w * 16 + i;
    const size_t q = rbase + (size_t)m * 512;
    half8 tv = *(const half8*)(t + q + d0);
    half8 sk = *(const half8*)(skip + q + d0);
    float v0 = (float)tv[0] + (float)sk[0], v1 = (float)tv[1] + (float)sk[1];
    float v2 = (float)tv[2] + (float)sk[2], v3 = (float)tv[3] + (float)sk[3];
    float v4 = (float)tv[4] + (float)sk[4], v5 = (float)tv[5] + (float)sk[5];
    float v6 = (float)tv[6] + (float)sk[6], v7 = (float)tv[7] + (float)sk[7];
    float s  = v0+v1+v2+v3+v4+v5+v6+v7;
    float ss = v0*v0+v1*v1+v2*v2+v3*v3+v4*v4+v5*v5+v6*v6+v7*v7;
#pragma unroll
    for (int msk = 1; msk < 64; msk <<= 1){ s += __shfl_xor(s, msk); ss += __shfl_xor(ss, msk); }
    const float mu = s * (1.f/512.f);
    const float rs = rsqrtf(ss * (1.f/512.f) - mu*mu + 1e-5f);
    half8 o;
    o[0] = (f16)((v0 - mu) * rs * g0.x + b0.x);
    o[1] = (f16)((v1 - mu) * rs * g0.y + b0.y);
    o[2] = (f16)((v2 - mu) * rs * g0.z + b0.z);
    o[3] = (f16)((v3 - mu) * rs * g0.w + b0.w);
    o[4] = (f16)((v4 - mu) * rs * g1.x + b1.x);
    o[5] = (f16)((v5 - mu) * rs * g1.y + b1.y);
    o[6] = (f16)((v6 - mu) * rs * g1.z + b1.z);
    o[7] = (f16)((v7 - mu) * rs * g1.w + b1.w);
    *(half8*)(Z + ZOFF(m, l * 16)) = o;
  }
  __syncthreads();

  // cross-attention, head h = w; lane = key row m
  const int h = w;
  const float* q = gq + (size_t)labels[cg] * 512 + h * 128;
  float s = 0.f;
#pragma unroll
  for (int d = 0; d < 128; d += 8){
    half8 v = *(const half8*)(Z + ZOFF(l, (h * 128 + d) * 2));
    float4 q0 = *(const float4*)&q[d];
    float4 q1 = *(const float4*)&q[d + 4];
    s += q0.x*(float)v[0] + q0.y*(float)v[1] + q0.z*(float)v[2] + q0.w*(float)v[3]
       + q1.x*(float)v[4] + q1.y*(float)v[5] + q1.z*(float)v[6] + q1.w*(float)v[7];
  }
  s *= SCALE;
  float mx = s;
#pragma unroll
  for (int msk = 1; msk < 64; msk <<= 1) mx = fmaxf(mx, __shfl_xor(mx, msk));
  float e = __expf(s - mx);
  float sm = e;
#pragma unroll
  for (int msk = 1; msk < 64; msk <<= 1) sm += __shfl_xor(sm, msk);
  const float wgt = e / sm;

  float a0 = 0.f, a1 = 0.f;
  for (int m = 0; m < 64; ++m){
    const float wm = __shfl(wgt, m);
    const f16* zm = (const f16*)(Z + ZOFF(m, (h * 128 + 2 * l) * 2));
    a0 += wm * (float)zm[0];
    a1 += wm * (float)zm[1];
  }
  float2 o; o.x = a0; o.y = a1;
  *(float2*)&out[(size_t)cg * 512 + h * 128 + 2 * l] = o;
}

// ---------------- launcher ----------------
extern "C" void kernel_launch(void* const* d_in, const int* in_sizes, int n_in,
                              void* d_out, int out_size, void* d_ws, size_t ws_size,
                              hipStream_t stream){
  (void)in_sizes; (void)n_in; (void)out_size;
  const float* protos = (const float*)d_in[0];
  const float* norm_g = (const float*)d_in[1];
  const float* norm_b = (const float*)d_in[2];
  const float* in_w   = (const float*)d_in[3];
  const float* in_b   = (const float*)d_in[4];
  const float* ow     = (const float*)d_in[5];
  const float* ob     = (const float*)d_in[6];
  const float* l1w    = (const float*)d_in[7];
  const float* l1b    = (const float*)d_in[8];
  const float* l2w    = (const float*)d_in[9];
  const float* l2b    = (const float*)d_in[10];
  const float* n1g    = (const float*)d_in[11];
  const float* n1b    = (const float*)d_in[12];
  const float* n2g    = (const float*)d_in[13];
  const float* n2b    = (const float*)d_in[14];
  const float* gq     = (const float*)d_in[15];
  const int*   labels = (const int*)d_in[16];
  float* out = (float*)d_out;

  char* p = (char*)d_ws;
  auto alloc = [&](size_t bytes)->char*{
    char* r = p; p += (bytes + 255) & ~(size_t)255; return r;
  };
  f16* Wq = (f16*)alloc((size_t)1536*512*2);
  f16* Wo = (f16*)alloc((size_t)512*512*2);
  f16* W1 = (f16*)alloc((size_t)2048*512*2);
  f16* W2 = (f16*)alloc((size_t)512*2048*2);
  const size_t fixed = (size_t)(p - (char*)d_ws);

  const size_t per_class = (size_t)64*512*2 + (size_t)64*2048*2 + (size_t)64*512*2 + (size_t)64*512*2;
  long long avail = (long long)ws_size - (long long)fixed - 8192;
  long long cc_max = avail > 0 ? avail / (long long)per_class : 0;
  int Cc = (int)(cc_max > 2000 ? 2000 : cc_max);
  Cc &= ~3;                       // 256-row (4-class) granularity
  if (Cc < 4) Cc = 4;

  f16* xb  = (f16*)alloc((size_t)Cc*64*512*2);
  f16* big = (f16*)alloc((size_t)Cc*64*2048*2);
  f16* sac = (f16*)alloc((size_t)Cc*64*512*2);
  f16* tmp = (f16*)alloc((size_t)Cc*64*512*2);

  k_cvt<<<1536*512/2048, 256, 0, stream>>>(in_w, Wq, 1536*512);
  k_cvt<<<512*512/2048,  256, 0, stream>>>(ow,   Wo, 512*512);
  k_cvt<<<2048*512/2048, 256, 0, stream>>>(l1w,  W1, 2048*512);
  k_cvt<<<2048*512/2048, 256, 0, stream>>>(l2w,  W2, 512*2048);

  const size_t SMEM = 131072;   // 2 bufs x 64 KiB
  for (int c0 = 0; c0 < 2000; c0 += Cc){
    const int cc = (2000 - c0 < Cc) ? (2000 - c0) : Cc;
    const int R = cc * 64;
    const int gm = R / 256;
    k_ln0<<<R/4, 256, 0, stream>>>(protos, norm_g, norm_b, xb, c0);
    k_gemm<false><<<512, 512, SMEM, stream>>>(xb, Wq, in_b, big, 1536, 512, gm, 6);
    k_attn<<<cc, 256, 0, stream>>>(big, sac);
    k_gemm<false><<<512, 512, SMEM, stream>>>(sac, Wo, ob, tmp, 512, 512, gm, 2);
    k_resln<<<R/4, 256, 0, stream>>>(tmp, xb, n1g, n1b, sac);           // sac now holds y
    k_gemm<true><<<512, 512, SMEM, stream>>>(sac, W1, l1b, big, 2048, 512, gm, 8);
    k_gemm<false><<<512, 512, SMEM, stream>>>(big, W2, l2b, tmp, 512, 2048, gm, 2);
    // residual(sac=y) + LN2 + cross fused
    k_resln_cross<<<cc, 256, 0, stream>>>(tmp, sac, n2g, n2b, gq, labels, out, c0);
  }
}

// Round 13
// 1434.266 us; speedup vs baseline: 1.1172x; 1.1172x over previous
//
#include <hip/hip_runtime.h>

typedef _Float16 f16;
typedef _Float16 half4 __attribute__((ext_vector_type(4)));
typedef _Float16 half8 __attribute__((ext_vector_type(8)));
typedef float f32x4 __attribute__((ext_vector_type(4)));

typedef __attribute__((address_space(1))) void* as1v;
typedef __attribute__((address_space(3))) void* as3v;

#define SCALE 0.08838834764831845f  // 1/sqrt(128)

static __device__ __forceinline__ f32x4 mfma16(half8 a, half8 b, f32x4 c){
  return __builtin_amdgcn_mfma_f32_16x16x32_f16(a, b, c, 0, 0, 0);
}

// ---------------- weight fp32 -> fp16 ----------------
__global__ __launch_bounds__(256) void k_cvt(const float* __restrict__ src, f16* __restrict__ dst, int n){
  int i = (blockIdx.x * 256 + threadIdx.x) * 8;
  if (i >= n) return;
  float4 a = *(const float4*)(src + i);
  float4 b = *(const float4*)(src + i + 4);
  half8 h;
  h[0] = (f16)a.x; h[1] = (f16)a.y; h[2] = (f16)a.z; h[3] = (f16)a.w;
  h[4] = (f16)b.x; h[5] = (f16)b.y; h[6] = (f16)b.z; h[7] = (f16)b.w;
  *(half8*)(dst + i) = h;
}

// ---------------- LN over protos, (M,C,D) -> chunk-local (cl,m,D) fp16 ----------------
__global__ __launch_bounds__(256) void k_ln0(const float* __restrict__ protos,
                                             const float* __restrict__ g,
                                             const float* __restrict__ bb,
                                             f16* __restrict__ xb, int c0){
  const int w = threadIdx.x >> 6, l = threadIdx.x & 63;
  const int q = blockIdx.x * 4 + w;
  const int cl = q >> 6, m = q & 63;
  const float* in = protos + ((size_t)m * 2000 + (size_t)(c0 + cl)) * 512;
  const int d0 = l * 8;
  float4 a = *(const float4*)(in + d0);
  float4 c = *(const float4*)(in + d0 + 4);
  float s  = a.x + a.y + a.z + a.w + c.x + c.y + c.z + c.w;
  float ss = a.x*a.x + a.y*a.y + a.z*a.z + a.w*a.w + c.x*c.x + c.y*c.y + c.z*c.z + c.w*c.w;
#pragma unroll
  for (int msk = 1; msk < 64; msk <<= 1){ s += __shfl_xor(s, msk); ss += __shfl_xor(ss, msk); }
  const float mu = s * (1.f/512.f);
  const float rs = rsqrtf(ss * (1.f/512.f) - mu*mu + 1e-5f);
  float4 g0 = *(const float4*)(g + d0),  g1 = *(const float4*)(g + d0 + 4);
  float4 b0 = *(const float4*)(bb + d0), b1 = *(const float4*)(bb + d0 + 4);
  half8 o;
  o[0] = (f16)((a.x - mu) * rs * g0.x + b0.x);
  o[1] = (f16)((a.y - mu) * rs * g0.y + b0.y);
  o[2] = (f16)((a.z - mu) * rs * g0.z + b0.z);
  o[3] = (f16)((a.w - mu) * rs * g0.w + b0.w);
  o[4] = (f16)((c.x - mu) * rs * g1.x + b1.x);
  o[5] = (f16)((c.y - mu) * rs * g1.y + b1.y);
  o[6] = (f16)((c.z - mu) * rs * g1.z + b1.z);
  o[7] = (f16)((c.w - mu) * rs * g1.w + b1.w);
  *(half8*)(xb + (size_t)q * 512 + d0) = o;
}

// ---------------- residual + LN:  out = LN(t_f16 + skip_f16) ----------------
__global__ __launch_bounds__(256) void k_resln(const f16* __restrict__ t, const f16* __restrict__ skip,
                                               const float* __restrict__ g, const float* __restrict__ bb,
                                               f16* __restrict__ outp){
  const int w = threadIdx.x >> 6, l = threadIdx.x & 63;
  const size_t q = (size_t)blockIdx.x * 4 + w;
  const int d0 = l * 8;
  half8 tv = *(const half8*)(t + q * 512 + d0);
  half8 sk = *(const half8*)(skip + q * 512 + d0);
  float v0 = (float)tv[0] + (float)sk[0], v1 = (float)tv[1] + (float)sk[1];
  float v2 = (float)tv[2] + (float)sk[2], v3 = (float)tv[3] + (float)sk[3];
  float v4 = (float)tv[4] + (float)sk[4], v5 = (float)tv[5] + (float)sk[5];
  float v6 = (float)tv[6] + (float)sk[6], v7 = (float)tv[7] + (float)sk[7];
  float s  = v0+v1+v2+v3+v4+v5+v6+v7;
  float ss = v0*v0+v1*v1+v2*v2+v3*v3+v4*v4+v5*v5+v6*v6+v7*v7;
#pragma unroll
  for (int msk = 1; msk < 64; msk <<= 1){ s += __shfl_xor(s, msk); ss += __shfl_xor(ss, msk); }
  const float mu = s * (1.f/512.f);
  const float rs = rsqrtf(ss * (1.f/512.f) - mu*mu + 1e-5f);
  float4 g0 = *(const float4*)(g + d0),  g1 = *(const float4*)(g + d0 + 4);
  float4 b0 = *(const float4*)(bb + d0), b1 = *(const float4*)(bb + d0 + 4);
  half8 o;
  o[0] = (f16)((v0 - mu) * rs * g0.x + b0.x);
  o[1] = (f16)((v1 - mu) * rs * g0.y + b0.y);
  o[2] = (f16)((v2 - mu) * rs * g0.z + b0.z);
  o[3] = (f16)((v3 - mu) * rs * g0.w + b0.w);
  o[4] = (f16)((v4 - mu) * rs * g1.x + b1.x);
  o[5] = (f16)((v5 - mu) * rs * g1.y + b1.y);
  o[6] = (f16)((v6 - mu) * rs * g1.z + b1.z);
  o[7] = (f16)((v7 - mu) * rs * g1.w + b1.w);
  *(half8*)(outp + q * 512 + d0) = o;
}

// ---------------- GEMM (r8 structure, best-known): C = A B^T + bias, opt ReLU ----
// 256x256 tile, BK=64, 8 waves 2Mx4N (wave-tile 128x64), LDS 128 KiB 2-dbuf,
// 4 phases/K-tile, counted vmcnt(2) once per tile, setprio MFMA clusters,
// XOR slot swizzle (pre-swizzled source), swapped-operand MFMA -> vec epilogue.
#define GLL(gp, lp) __builtin_amdgcn_global_load_lds((as1v)(void*)(gp), (as3v)(lp), 16, 0, 0)

template<bool RELU>
__global__ __launch_bounds__(512, 2) void k_gemm(const f16* __restrict__ A, const f16* __restrict__ B,
                                                 const float* __restrict__ bias, f16* __restrict__ Cout,
                                                 int N, int K, int gn){
  extern __shared__ char smem_raw[];
  f16* lds = (f16*)smem_raw;   // 2 bufs x 32768 f16; per buf: A halves @0,8192; B halves @16384,24576

  const int t = threadIdx.x, w = t >> 6, l = t & 63;
  const int wr = w >> 2, wc = w & 3;

  const int nwg = gridDim.x;
  const int q8 = nwg >> 3, r8 = nwg & 7;
  const int xcd = blockIdx.x & 7, lidx = blockIdx.x >> 3;
  const int swz = (xcd < r8 ? xcd * (q8 + 1) : r8 * (q8 + 1) + (xcd - r8) * q8) + lidx;
  const int tm = swz / gn, tn = swz % gn;
  const size_t row0 = (size_t)tm * 256;
  const int col0 = tn * 256;

  f32x4 acc[8][4];
#pragma unroll
  for (int m = 0; m < 8; ++m)
#pragma unroll
    for (int n = 0; n < 4; ++n) acc[m][n] = (f32x4){0.f,0.f,0.f,0.f};

  const int lsw = ((t & 7) ^ ((t >> 3) & 7)) * 8;
  const f16* gAb = A + (row0 + (size_t)(t >> 3)) * (size_t)K + lsw;
  const f16* gBb = B + ((size_t)col0 + (size_t)(t >> 3)) * (size_t)K + lsw;
  const int t8 = t * 8;

  const int rA  = (l & 15) * 64;
  const int ps0 = (((l >> 4) ^ (l & 7)) << 3);
  const int ps1 = (((4 + (l >> 4)) ^ (l & 7)) << 3);
  const int abase = wr * 8192 + rA;
  const int bbase = 16384 + wc * 4096 + rA;

  const int NT = K >> 6;

  auto stgA = [&](int tt, int h){
    f16* d = lds + (tt & 1) * 32768 + h * 8192 + t8;
    const f16* s = gAb + (size_t)(h * 128) * K + (size_t)tt * 64;
    GLL(s, d);
    GLL(s + (size_t)64 * K, d + 4096);
  };
  auto stgB = [&](int tt, int h){
    f16* d = lds + (tt & 1) * 32768 + 16384 + h * 8192 + t8;
    const f16* s = gBb + (size_t)(h * 128) * K + (size_t)tt * 64;
    GLL(s, d);
    GLL(s + (size_t)64 * K, d + 4096);
  };

  stgA(0, 0); stgA(0, 1); stgB(0, 0); stgB(0, 1);
  if (NT > 1){
    stgA(1, 0);
    asm volatile("s_waitcnt vmcnt(2)" ::: "memory");
  } else {
    asm volatile("s_waitcnt vmcnt(0)" ::: "memory");
  }
  __builtin_amdgcn_s_barrier();

  for (int tt = 0; tt < NT; ++tt){
    const f16* sb = lds + (tt & 1) * 32768;
    const bool s1 = tt + 1 < NT, s2 = tt + 2 < NT;
    half8 af03[4][2], af47[4][2], bf[4][2];

#pragma unroll
    for (int m = 0; m < 4; ++m){
      af03[m][0] = *(const half8*)(sb + abase + m * 1024 + ps0);
      af03[m][1] = *(const half8*)(sb + abase + m * 1024 + ps1);
    }
#pragma unroll
    for (int n = 0; n < 2; ++n){
      bf[n][0] = *(const half8*)(sb + bbase + n * 1024 + ps0);
      bf[n][1] = *(const half8*)(sb + bbase + n * 1024 + ps1);
    }
    if (s1) stgA(tt + 1, 1);
    __builtin_amdgcn_s_barrier();
    asm volatile("s_waitcnt lgkmcnt(0)" ::: "memory");
    __builtin_amdgcn_sched_barrier(0);
    __builtin_amdgcn_s_setprio(1);
#pragma unroll
    for (int ks = 0; ks < 2; ++ks)
#pragma unroll
      for (int m = 0; m < 4; ++m)
#pragma unroll
        for (int n = 0; n < 2; ++n)
          acc[m][n] = mfma16(bf[n][ks], af03[m][ks], acc[m][n]);
    __builtin_amdgcn_s_setprio(0);
    __builtin_amdgcn_s_barrier();

#pragma unroll
    for (int n = 2; n < 4; ++n){
      bf[n][0] = *(const half8*)(sb + bbase + n * 1024 + ps0);
      bf[n][1] = *(const half8*)(sb + bbase + n * 1024 + ps1);
    }
    if (s1) stgB(tt + 1, 0);
    __builtin_amdgcn_s_barrier();
    asm volatile("s_waitcnt lgkmcnt(0)" ::: "memory");
    __builtin_amdgcn_sched_barrier(0);
    __builtin_amdgcn_s_setprio(1);
#pragma unroll
    for (int ks = 0; ks < 2; ++ks)
#pragma unroll
      for (int m = 0; m < 4; ++m)
#pragma unroll
        for (int n = 2; n < 4; ++n)
          acc[m][n] = mfma16(bf[n][ks], af03[m][ks], acc[m][n]);
    __builtin_amdgcn_s_setprio(0);
    __builtin_amdgcn_s_barrier();

#pragma unroll
    for (int m = 0; m < 4; ++m){
      af47[m][0] = *(const half8*)(sb + abase + (m + 4) * 1024 + ps0);
      af47[m][1] = *(const half8*)(sb + abase + (m + 4) * 1024 + ps1);
    }
    if (s1) stgB(tt + 1, 1);
    __builtin_amdgcn_s_barrier();
    asm volatile("s_waitcnt lgkmcnt(0)" ::: "memory");
    __builtin_amdgcn_sched_barrier(0);
    __builtin_amdgcn_s_setprio(1);
#pragma unroll
    for (int ks = 0; ks < 2; ++ks)
#pragma unroll
      for (int m = 0; m < 4; ++m)
#pragma unroll
        for (int n = 0; n < 2; ++n)
          acc[m + 4][n] = mfma16(bf[n][ks], af47[m][ks], acc[m + 4][n]);
    __builtin_amdgcn_s_setprio(0);
    __builtin_amdgcn_s_barrier();

    if (s2) stgA(tt + 2, 0);
    __builtin_amdgcn_s_barrier();
    __builtin_amdgcn_s_setprio(1);
#pragma unroll
    for (int ks = 0; ks < 2; ++ks)
#pragma unroll
      for (int m = 0; m < 4; ++m)
#pragma unroll
        for (int n = 2; n < 4; ++n)
          acc[m + 4][n] = mfma16(bf[n][ks], af47[m][ks], acc[m + 4][n]);
    __builtin_amdgcn_s_setprio(0);
    if (s1){
      if (s2) { asm volatile("s_waitcnt vmcnt(2)" ::: "memory"); }
      else    { asm volatile("s_waitcnt vmcnt(0)" ::: "memory"); }
    }
    __builtin_amdgcn_s_barrier();
  }

#pragma unroll
  for (int n = 0; n < 4; ++n){
    const int c = col0 + wc * 64 + n * 16 + ((l >> 4) << 2);
    float4 b4 = *(const float4*)(bias + c);
#pragma unroll
    for (int m = 0; m < 8; ++m){
      const size_t r = row0 + (size_t)(wr * 128 + m * 16 + (l & 15));
      float v0 = acc[m][n][0] + b4.x;
      float v1 = acc[m][n][1] + b4.y;
      float v2 = acc[m][n][2] + b4.z;
      float v3 = acc[m][n][3] + b4.w;
      if (RELU){ v0 = fmaxf(v0, 0.f); v1 = fmaxf(v1, 0.f); v2 = fmaxf(v2, 0.f); v3 = fmaxf(v3, 0.f); }
      half4 h; h[0] = (f16)v0; h[1] = (f16)v1; h[2] = (f16)v2; h[3] = (f16)v3;
      *(half4*)&Cout[r * (size_t)N + c] = h;
    }
  }
}

// ---------------- per-class 4-head self-attention (M=64, HD=128) ----------------
__global__ __launch_bounds__(256) void k_attn(const f16* __restrict__ qkv, f16* __restrict__ sa){
  __shared__ __align__(16) f16 P[4][4096];
  __shared__ __align__(16) f16 VT[4][4096];
  const int cl = blockIdx.x;
  const int h = threadIdx.x >> 6, l = threadIdx.x & 63;
  const f16* base = qkv + (size_t)cl * 64 * 1536;
  const f16* Qp = base + h * 128;
  const f16* Kp = base + 512 + h * 128;
  const f16* Vp = base + 1024 + h * 128;

  f32x4 s[4][4];
#pragma unroll
  for (int x = 0; x < 4; ++x)
#pragma unroll
    for (int y = 0; y < 4; ++y) s[x][y] = (f32x4){0.f,0.f,0.f,0.f};
#pragma unroll
  for (int ks = 0; ks < 4; ++ks){
    half8 aq[4], bk[4];
#pragma unroll
    for (int x = 0; x < 4; ++x)
      aq[x] = *(const half8*)&Qp[(size_t)(x * 16 + (l & 15)) * 1536 + ks * 32 + (l >> 4) * 8];
#pragma unroll
    for (int y = 0; y < 4; ++y)
      bk[y] = *(const half8*)&Kp[(size_t)(y * 16 + (l & 15)) * 1536 + ks * 32 + (l >> 4) * 8];
#pragma unroll
    for (int x = 0; x < 4; ++x)
#pragma unroll
      for (int y = 0; y < 4; ++y)
        s[x][y] = mfma16(aq[x], bk[y], s[x][y]);
  }

  char* Pb = (char*)&P[h][0];
#pragma unroll
  for (int x = 0; x < 4; ++x){
#pragma unroll
    for (int j = 0; j < 4; ++j){
      float e0 = s[x][0][j] * SCALE;
      float e1 = s[x][1][j] * SCALE;
      float e2 = s[x][2][j] * SCALE;
      float e3 = s[x][3][j] * SCALE;
      float mx = fmaxf(fmaxf(e0, e1), fmaxf(e2, e3));
#pragma unroll
      for (int msk = 1; msk < 16; msk <<= 1) mx = fmaxf(mx, __shfl_xor(mx, msk));
      e0 = __expf(e0 - mx); e1 = __expf(e1 - mx); e2 = __expf(e2 - mx); e3 = __expf(e3 - mx);
      float sm = e0 + e1 + e2 + e3;
#pragma unroll
      for (int msk = 1; msk < 16; msk <<= 1) sm += __shfl_xor(sm, msk);
      const float inv = 1.f / sm;
      const int row = x * 16 + (l >> 4) * 4 + j;
      const int rb = row * 128 + (l & 15) * 2;
      const int rsw = (row & 7) << 4;
      *(f16*)(Pb + ((rb     ) ^ rsw)) = (f16)(e0 * inv);
      *(f16*)(Pb + ((rb + 32) ^ rsw)) = (f16)(e1 * inv);
      *(f16*)(Pb + ((rb + 64) ^ rsw)) = (f16)(e2 * inv);
      *(f16*)(Pb + ((rb + 96) ^ rsw)) = (f16)(e3 * inv);
    }
  }

  char* Vb = (char*)&VT[h][0];
#pragma unroll
  for (int dh = 0; dh < 2; ++dh){
#pragma unroll
    for (int it = 0; it < 8; ++it){
      const int chunk = it * 64 + l;
      const int m = chunk >> 3, dc = chunk & 7;
      half8 v = *(const half8*)&Vp[(size_t)m * 1536 + dh * 64 + dc * 8];
#pragma unroll
      for (int jj = 0; jj < 8; ++jj){
        const int dd = dc * 8 + jj;
        *(f16*)(Vb + ((dd * 128 + m * 2) ^ ((dd & 7) << 4))) = v[jj];
      }
    }
    __syncthreads();
#pragma unroll
    for (int x = 0; x < 4; ++x){
      const int ar = x * 16 + (l & 15);
      const int ab = ar * 128, sw = (ar & 7) << 4;
      half8 ap0 = *(const half8*)(Pb + ((ab + (l >> 4) * 16) ^ sw));
      half8 ap1 = *(const half8*)(Pb + ((ab + 64 + (l >> 4) * 16) ^ sw));
#pragma unroll
      for (int dt = 0; dt < 4; ++dt){
        const int vr = dt * 16 + (l & 15);
        const int vb = vr * 128, vsw = (vr & 7) << 4;
        half8 b0 = *(const half8*)(Vb + ((vb + (l >> 4) * 16) ^ vsw));
        half8 b1 = *(const half8*)(Vb + ((vb + 64 + (l >> 4) * 16) ^ vsw));
        f32x4 o = (f32x4){0.f,0.f,0.f,0.f};
        o = mfma16(ap0, b0, o);
        o = mfma16(ap1, b1, o);
#pragma unroll
        for (int j = 0; j < 4; ++j){
          const int mrow = x * 16 + (l >> 4) * 4 + j;
          const int dcol = dh * 64 + dt * 16 + (l & 15);
          sa[((size_t)cl * 64 + mrow) * 512 + h * 128 + dcol] = (f16)o[j];
        }
      }
    }
    __syncthreads();
  }
}

// ---------------- fused residual + LN2 + cross-attention -> fp32 out ----------------
// Block = 1 class (4 waves). (a) each wave LNs 16 rows of z = t+skip, storing
// z into XOR-swizzled LDS (5-bit row swizzle -> conflict-free strided reads);
// (b) per-head cross-attn reads z from LDS. Deletes the z HBM round-trip.
#define ZOFF(m, cb) (((m) * 1024 + (cb)) ^ (((m) & 31) << 4))
__global__ __launch_bounds__(256) void k_resln_cross(const f16* __restrict__ t, const f16* __restrict__ skip,
                                                     const float* __restrict__ g, const float* __restrict__ bb,
                                                     const float* __restrict__ gq, const int* __restrict__ labels,
                                                     float* __restrict__ out, int c0){
  __shared__ __align__(16) char Z[65536];   // z[64][512] f16, row-swizzled
  const int cl = blockIdx.x;
  const int w = threadIdx.x >> 6, l = threadIdx.x & 63;
  const int cg = c0 + cl;
  const size_t rbase = (size_t)cl * 64 * 512;
  const int d0 = l * 8;

  float4 g0 = *(const float4*)(g + d0),  g1 = *(const float4*)(g + d0 + 4);
  float4 b0 = *(const float4*)(bb + d0), b1 = *(const float4*)(bb + d0 + 4);

#pragma unroll 4
  for (int i = 0; i < 16; ++i){
    const int m = w * 16 + i;
    const size_t q = rbase + (size_t)m * 512;
    half8 tv = *(const half8*)(t + q + d0);
    half8 sk = *(const half8*)(skip + q + d0);
    float v0 = (float)tv[0] + (float)sk[0], v1 = (float)tv[1] + (float)sk[1];
    float v2 = (float)tv[2] + (float)sk[2], v3 = (float)tv[3] + (float)sk[3];
    float v4 = (float)tv[4] + (float)sk[4], v5 = (float)tv[5] + (float)sk[5];
    float v6 = (float)tv[6] + (float)sk[6], v7 = (float)tv[7] + (float)sk[7];
    float s  = v0+v1+v2+v3+v4+v5+v6+v7;
    float ss = v0*v0+v1*v1+v2*v2+v3*v3+v4*v4+v5*v5+v6*v6+v7*v7;
#pragma unroll
    for (int msk = 1; msk < 64; msk <<= 1){ s += __shfl_xor(s, msk); ss += __shfl_xor(ss, msk); }
    const float mu = s * (1.f/512.f);
    const float rs = rsqrtf(ss * (1.f/512.f) - mu*mu + 1e-5f);
    half8 o;
    o[0] = (f16)((v0 - mu) * rs * g0.x + b0.x);
    o[1] = (f16)((v1 - mu) * rs * g0.y + b0.y);
    o[2] = (f16)((v2 - mu) * rs * g0.z + b0.z);
    o[3] = (f16)((v3 - mu) * rs * g0.w + b0.w);
    o[4] = (f16)((v4 - mu) * rs * g1.x + b1.x);
    o[5] = (f16)((v5 - mu) * rs * g1.y + b1.y);
    o[6] = (f16)((v6 - mu) * rs * g1.z + b1.z);
    o[7] = (f16)((v7 - mu) * rs * g1.w + b1.w);
    *(half8*)(Z + ZOFF(m, l * 16)) = o;
  }
  __syncthreads();

  // cross-attention, head h = w; lane = key row m
  const int h = w;
  const float* q = gq + (size_t)labels[cg] * 512 + h * 128;
  float s = 0.f;
#pragma unroll
  for (int d = 0; d < 128; d += 8){
    half8 v = *(const half8*)(Z + ZOFF(l, (h * 128 + d) * 2));
    float4 q0 = *(const float4*)&q[d];
    float4 q1 = *(const float4*)&q[d + 4];
    s += q0.x*(float)v[0] + q0.y*(float)v[1] + q0.z*(float)v[2] + q0.w*(float)v[3]
       + q1.x*(float)v[4] + q1.y*(float)v[5] + q1.z*(float)v[6] + q1.w*(float)v[7];
  }
  s *= SCALE;
  float mx = s;
#pragma unroll
  for (int msk = 1; msk < 64; msk <<= 1) mx = fmaxf(mx, __shfl_xor(mx, msk));
  float e = __expf(s - mx);
  float sm = e;
#pragma unroll
  for (int msk = 1; msk < 64; msk <<= 1) sm += __shfl_xor(sm, msk);
  const float wgt = e / sm;

  float a0 = 0.f, a1 = 0.f;
  for (int m = 0; m < 64; ++m){
    const float wm = __shfl(wgt, m);
    const f16* zm = (const f16*)(Z + ZOFF(m, (h * 128 + 2 * l) * 2));
    a0 += wm * (float)zm[0];
    a1 += wm * (float)zm[1];
  }
  float2 o; o.x = a0; o.y = a1;
  *(float2*)&out[(size_t)cg * 512 + h * 128 + 2 * l] = o;
}

// ---------------- launcher ----------------
extern "C" void kernel_launch(void* const* d_in, const int* in_sizes, int n_in,
                              void* d_out, int out_size, void* d_ws, size_t ws_size,
                              hipStream_t stream){
  (void)in_sizes; (void)n_in; (void)out_size;
  const float* protos = (const float*)d_in[0];
  const float* norm_g = (const float*)d_in[1];
  const float* norm_b = (const float*)d_in[2];
  const float* in_w   = (const float*)d_in[3];
  const float* in_b   = (const float*)d_in[4];
  const float* ow     = (const float*)d_in[5];
  const float* ob     = (const float*)d_in[6];
  const float* l1w    = (const float*)d_in[7];
  const float* l1b    = (const float*)d_in[8];
  const float* l2w    = (const float*)d_in[9];
  const float* l2b    = (const float*)d_in[10];
  const float* n1g    = (const float*)d_in[11];
  const float* n1b    = (const float*)d_in[12];
  const float* n2g    = (const float*)d_in[13];
  const float* n2b    = (const float*)d_in[14];
  const float* gq     = (const float*)d_in[15];
  const int*   labels = (const int*)d_in[16];
  float* out = (float*)d_out;

  char* p = (char*)d_ws;
  auto alloc = [&](size_t bytes)->char*{
    char* r = p; p += (bytes + 255) & ~(size_t)255; return r;
  };
  f16* Wq = (f16*)alloc((size_t)1536*512*2);
  f16* Wo = (f16*)alloc((size_t)512*512*2);
  f16* W1 = (f16*)alloc((size_t)2048*512*2);
  f16* W2 = (f16*)alloc((size_t)512*2048*2);
  const size_t fixed = (size_t)(p - (char*)d_ws);

  const size_t per_class = (size_t)64*512*2 + (size_t)64*2048*2 + (size_t)64*512*2 + (size_t)64*512*2;
  long long avail = (long long)ws_size - (long long)fixed - 8192;
  long long cc_max = avail > 0 ? avail / (long long)per_class : 0;
  int Cc = (int)(cc_max > 2000 ? 2000 : cc_max);
  Cc &= ~3;                       // 256-row (4-class) granularity
  if (Cc < 4) Cc = 4;

  f16* xb  = (f16*)alloc((size_t)Cc*64*512*2);
  f16* big = (f16*)alloc((size_t)Cc*64*2048*2);
  f16* sac = (f16*)alloc((size_t)Cc*64*512*2);
  f16* tmp = (f16*)alloc((size_t)Cc*64*512*2);

  k_cvt<<<1536*512/2048, 256, 0, stream>>>(in_w, Wq, 1536*512);
  k_cvt<<<512*512/2048,  256, 0, stream>>>(ow,   Wo, 512*512);
  k_cvt<<<2048*512/2048, 256, 0, stream>>>(l1w,  W1, 2048*512);
  k_cvt<<<2048*512/2048, 256, 0, stream>>>(l2w,  W2, 512*2048);

  const size_t SMEM = 131072;   // 2 bufs x 64 KiB
  for (int c0 = 0; c0 < 2000; c0 += Cc){
    const int cc = (2000 - c0 < Cc) ? (2000 - c0) : Cc;
    const int R = cc * 64;
    const int gm = R / 256;
    k_ln0<<<R/4, 256, 0, stream>>>(protos, norm_g, norm_b, xb, c0);
    k_gemm<false><<<gm*6, 512, SMEM, stream>>>(xb, Wq, in_b, big, 1536, 512, 6);
    k_attn<<<cc, 256, 0, stream>>>(big, sac);
    k_gemm<false><<<gm*2, 512, SMEM, stream>>>(sac, Wo, ob, tmp, 512, 512, 2);
    k_resln<<<R/4, 256, 0, stream>>>(tmp, xb, n1g, n1b, sac);           // sac now holds y
    k_gemm<true><<<gm*8, 512, SMEM, stream>>>(sac, W1, l1b, big, 2048, 512, 8);
    k_gemm<false><<<gm*2, 512, SMEM, stream>>>(big, W2, l2b, tmp, 512, 2048, 2);
    // residual(sac=y) + LN2 + cross-attention fused
    k_resln_cross<<<cc, 256, 0, stream>>>(tmp, sac, n2g, n2b, gq, labels, out, c0);
  }
}